// Round 12
// baseline (196.097 us; speedup 1.0000x reference)
//
#include <hip/hip_runtime.h>

#define N_NODES 100000
#define N_EDGES 1600000
#define D 64

// fine buckets: 32 nodes, 100000/32 = 3125 exactly
#define FSHIFT 5
#define FNODES 32
#define NFB 3125
#define CAPF 768            // mean 512, sigma ~22.6 -> +11.3 sigma

// coarse buckets: 2048 nodes
#define CSHIFT 11
#define CNODES 2048
#define NCB 49
#define CCAP 36864          // mean 32768, +22 sigma
#define FPC 64

#define CHUNK 4096
#define EPT 16
#define NCHUNKA 391         // ceil(1600000/4096)
#define NCHUNKB 9           // CCAP / 4096
#define NSB (NCB * NCHUNKB) // 441 scatB blocks
#define NXF 1563            // total xform tiles (1563*64 = 100032)
#define XFA 700             // xform tiles in K1 (fills scatA's idle CUs)
#define XFB (NXF - XFA)     // 863 xform tiles in K2

#define COLBITS 17
#define COLMASK 0x1FFFF

// ws layout (bytes)
#define CCUR_OFF   0           // int[49]   counts (zero-init)
#define FCUR_OFF   256         // int[3125] counts (zero-init)
#define INIT_BYTES 12756
#define DINV_OFF   16384       // float[100000]
#define Y_OFF      417792      // bf16[100000*64] UNSCALED x@W^T
#define CPAIRS_OFF 13217792    // int[49*36864]
#define FPAIRS_OFF 20443136    // int[3125*768]

typedef float fvec4 __attribute__((ext_vector_type(4)));

__device__ __forceinline__ unsigned f2bf(float f) {
    unsigned bits = __float_as_uint(f);
    return (bits + 0x7FFFu + ((bits >> 16) & 1u)) >> 16;
}

// y[n] = bf16(x[n] @ W^T)  -- NO dinv scaling (applied per-edge in mega).
__device__ __forceinline__ void xform_tile(int nb0, float* smem, int t,
        const float* __restrict__ x, const float* __restrict__ W,
        unsigned short* __restrict__ y) {
    float* XT = smem;               // XT[d*68 + n]
    float* WT = smem + 64 * 68;     // WT[d*68 + j]
    for (int i = t; i < D * D; i += 256) {
        int j = i >> 6, d = i & 63;
        WT[d * 68 + j] = W[i];
    }
    for (int i = t; i < 64 * D; i += 256) {
        int n = i >> 6, d = i & 63;
        int g = nb0 + n;
        XT[d * 68 + n] = (g < N_NODES) ? x[(size_t)g * D + d] : 0.0f;
    }
    __syncthreads();
    int tj = t & 15, tn = t >> 4;
    float4 a0 = {0,0,0,0}, a1 = {0,0,0,0}, a2 = {0,0,0,0}, a3 = {0,0,0,0};
#pragma unroll 8
    for (int d = 0; d < D; ++d) {
        float4 xv = *(const float4*)&XT[d * 68 + tn * 4];
        float4 wv = *(const float4*)&WT[d * 68 + tj * 4];
        a0.x = fmaf(xv.x, wv.x, a0.x); a0.y = fmaf(xv.x, wv.y, a0.y);
        a0.z = fmaf(xv.x, wv.z, a0.z); a0.w = fmaf(xv.x, wv.w, a0.w);
        a1.x = fmaf(xv.y, wv.x, a1.x); a1.y = fmaf(xv.y, wv.y, a1.y);
        a1.z = fmaf(xv.y, wv.z, a1.z); a1.w = fmaf(xv.y, wv.w, a1.w);
        a2.x = fmaf(xv.z, wv.x, a2.x); a2.y = fmaf(xv.z, wv.y, a2.y);
        a2.z = fmaf(xv.z, wv.z, a2.z); a2.w = fmaf(xv.z, wv.w, a2.w);
        a3.x = fmaf(xv.w, wv.x, a3.x); a3.y = fmaf(xv.w, wv.y, a3.y);
        a3.z = fmaf(xv.w, wv.z, a3.z); a3.w = fmaf(xv.w, wv.w, a3.w);
    }
    int jb = tj * 4;
#pragma unroll
    for (int s = 0; s < 4; ++s) {
        int g = nb0 + tn * 4 + s;
        if (g < N_NODES) {
            float4 a = (s == 0) ? a0 : (s == 1) ? a1 : (s == 2) ? a2 : a3;
            unsigned lo = f2bf(a.x) | (f2bf(a.y) << 16);
            unsigned hi = f2bf(a.z) | (f2bf(a.w) << 16);
            *(uint2*)(y + (size_t)g * D + jb) = make_uint2(lo, hi);
        }
    }
}

// K1: blocks [0,391) = scatA (R7-exact coarse scatter);
//     blocks [391,391+700) = xform tiles 0..699 (independent -> fills CUs).
__global__ __launch_bounds__(256) void saxf_kernel(
        const int* __restrict__ row, const int* __restrict__ col,
        int* __restrict__ ccur, int* __restrict__ cpairs,
        const float* __restrict__ x, const float* __restrict__ W,
        unsigned short* __restrict__ y) {
    __shared__ __align__(16) float smem[2 * 64 * 68];
    int t = threadIdx.x;
    int blk = blockIdx.x;
    if (blk >= NCHUNKA) {
        xform_tile((blk - NCHUNKA) << 6, smem, t, x, W, y);
        return;
    }
    int* lcnt = (int*)smem;
    int base = blk * CHUNK;
    if (t < NCB) lcnt[t] = 0;
    __syncthreads();
    int r[EPT], c[EPT], pos[EPT];
#pragma unroll
    for (int i = 0; i < EPT; ++i) {
        int e = base + i * 256 + t;
        if (e < N_EDGES) {
            r[i] = row[e];
            c[i] = col[e];
            pos[i] = atomicAdd(&lcnt[r[i] >> CSHIFT], 1);
        } else r[i] = -1;
    }
    __syncthreads();
    if (t < NCB) {
        int cc = lcnt[t];
        if (cc) lcnt[t] = t * CCAP + atomicAdd(&ccur[t], cc);
    }
    __syncthreads();
#pragma unroll
    for (int i = 0; i < EPT; ++i) {
        if (r[i] >= 0) {
            int cb = r[i] >> CSHIFT;
            int rl = r[i] & (CNODES - 1);
            cpairs[lcnt[cb] + pos[i]] = (rl << COLBITS) | c[i];
        }
    }
}

// K2: blocks [0,49) = dinv (2048-wide LDS hist of my coarse region, fire-and-
//     forget atomics, non-atomic global write);
//     blocks [49,49+441) = scatB (R7-exact fine scatter);
//     blocks [490,490+863) = xform tiles 700..1562.
__global__ __launch_bounds__(256) void dsbxf_kernel(
        const int* __restrict__ cpairs, const int* __restrict__ ccur,
        int* __restrict__ fcur, int* __restrict__ fpairs,
        float* __restrict__ dinv,
        const float* __restrict__ x, const float* __restrict__ W,
        unsigned short* __restrict__ y) {
    __shared__ __align__(16) float smem[2 * 64 * 68];
    int t = threadIdx.x;
    int blk = blockIdx.x;
    if (blk < NCB) {
        // ---- dinv role ----
        int* hist = (int*)smem;
        int cb = blk;
        for (int i = t; i < CNODES; i += 256) hist[i] = 0;
        __syncthreads();
        int beg = cb * CCAP;
        int end = beg + ccur[cb];
        for (int k = beg + t; k < end; k += 256)
            atomicAdd(&hist[cpairs[k] >> COLBITS], 1);
        __syncthreads();
        for (int i = t; i < CNODES; i += 256) {
            int n = (cb << CSHIFT) + i;
            if (n < N_NODES) {
                int d = hist[i];
                dinv[n] = (d > 0) ? rsqrtf((float)d) : 0.0f;
            }
        }
        return;
    }
    if (blk >= NCB + NSB) {
        xform_tile((XFA + blk - NCB - NSB) << 6, smem, t, x, W, y);
        return;
    }
    // ---- scatB role ----
    int* lcnt = (int*)smem;
    int bb = blk - NCB;
    int cb = bb / NCHUNKB;
    int k  = bb % NCHUNKB;
    int beg = cb * CCAP + k * CHUNK;
    int end = cb * CCAP + ccur[cb];
    if (end > beg + CHUNK) end = beg + CHUNK;
    if (t < FPC) lcnt[t] = 0;
    __syncthreads();
    int pc[EPT], pos[EPT];
#pragma unroll
    for (int i = 0; i < EPT; ++i) {
        int e = beg + i * 256 + t;
        if (e < end) {
            pc[i] = cpairs[e];
            pos[i] = atomicAdd(&lcnt[pc[i] >> (COLBITS + FSHIFT)], 1);
        } else pc[i] = -1;
    }
    __syncthreads();
    if (t < FPC) {
        int cc = lcnt[t];
        if (cc) {
            int fb = (cb << 6) + t;
            lcnt[t] = fb * CAPF + atomicAdd(&fcur[fb], cc);
        }
    }
    __syncthreads();
#pragma unroll
    for (int i = 0; i < EPT; ++i) {
        if (pc[i] >= 0) {
            int fl = pc[i] >> (COLBITS + FSHIFT);
            int rl5 = (pc[i] >> COLBITS) & (FNODES - 1);
            fpairs[lcnt[fl] + pos[i]] = (rl5 << COLBITS) | (pc[i] & COLMASK);
        }
    }
}

// Per fine bucket (32 nodes): hist -> scan -> bin(+dinv sidecar) -> wide gather.
// fpairs cached in 3 regs (read once); dinv[col] prefetched in hist phase,
// latency hidden across the scan barriers; gather fma-scales by lds_dinv[e].
__global__ __launch_bounds__(256) void mega_kernel(
        const int* __restrict__ fpairs, const int* __restrict__ fcur,
        const unsigned short* __restrict__ y, const float* __restrict__ dinv_g,
        const float* __restrict__ bias, float* __restrict__ out) {
    __shared__ int hist[FNODES];
    __shared__ int sc[FNODES];
    __shared__ int lrptr[FNODES + 1];
    __shared__ int lcur[FNODES];
    __shared__ float dl[FNODES];
    __shared__ int lds_scol[CAPF];
    __shared__ float lds_dinv[CAPF];
    int t = threadIdx.x;
    int b = blockIdx.x;
    int beg = b * CAPF;
    int cnt = fcur[b];
    if (t < FNODES) hist[t] = 0;
    __syncthreads();
    int p0 = -1, p1 = -1, p2 = -1;
    float d0 = 0.0f, d1 = 0.0f, d2 = 0.0f;
    if (t < cnt)       { p0 = fpairs[beg + t];       d0 = dinv_g[p0 & COLMASK]; }
    if (t + 256 < cnt) { p1 = fpairs[beg + t + 256]; d1 = dinv_g[p1 & COLMASK]; }
    if (t + 512 < cnt) { p2 = fpairs[beg + t + 512]; d2 = dinv_g[p2 & COLMASK]; }
    if (p0 >= 0) atomicAdd(&hist[p0 >> COLBITS], 1);
    if (p1 >= 0) atomicAdd(&hist[p1 >> COLBITS], 1);
    if (p2 >= 0) atomicAdd(&hist[p2 >> COLBITS], 1);
    __syncthreads();
    if (t < FNODES) sc[t] = hist[t];
    __syncthreads();
    for (int off = 1; off < FNODES; off <<= 1) {
        int v = (t < FNODES && t >= off) ? sc[t - off] : 0;
        __syncthreads();
        if (t < FNODES) sc[t] += v;
        __syncthreads();
    }
    if (t < FNODES) {
        lrptr[t + 1] = sc[t];
        lcur[t] = sc[t] - hist[t];
        dl[t] = (hist[t] > 0) ? rsqrtf((float)hist[t]) : 0.0f;
    }
    if (t == 0) lrptr[0] = 0;
    __syncthreads();
    if (p0 >= 0) {
        int pos = atomicAdd(&lcur[p0 >> COLBITS], 1);
        lds_scol[pos] = p0 & COLMASK;
        lds_dinv[pos] = d0;
    }
    if (p1 >= 0) {
        int pos = atomicAdd(&lcur[p1 >> COLBITS], 1);
        lds_scol[pos] = p1 & COLMASK;
        lds_dinv[pos] = d1;
    }
    if (p2 >= 0) {
        int pos = atomicAdd(&lcur[p2 >> COLBITS], 1);
        lds_scol[pos] = p2 & COLMASK;
        lds_dinv[pos] = d2;
    }
    __syncthreads();
    int wave = t >> 6;
    int lane = t & 63;
    int g = lane >> 3;     // edge slot 0..7
    int q = lane & 7;      // feature block
    float bj[8];
    {
        float4 b0 = *(const float4*)(bias + q * 8);
        float4 b1 = *(const float4*)(bias + q * 8 + 4);
        bj[0] = b0.x; bj[1] = b0.y; bj[2] = b0.z; bj[3] = b0.w;
        bj[4] = b1.x; bj[5] = b1.y; bj[6] = b1.z; bj[7] = b1.w;
    }
    for (int ln = wave; ln < FNODES; ln += 4) {
        int s = lrptr[ln], e2 = lrptr[ln + 1];
        float a[8];
#pragma unroll
        for (int i = 0; i < 8; ++i) a[i] = 0.0f;
        for (int k = s; k < e2; k += 32) {
#pragma unroll
            for (int u = 0; u < 4; ++u) {
                int e = k + u * 8 + g;
                if (e < e2) {
                    int c = lds_scol[e];
                    float dvc = lds_dinv[e];
                    uint4 v = *(const uint4*)(y + (size_t)c * D + q * 8);
                    a[0] = fmaf(dvc, __uint_as_float(v.x << 16), a[0]);
                    a[1] = fmaf(dvc, __uint_as_float(v.x & 0xffff0000u), a[1]);
                    a[2] = fmaf(dvc, __uint_as_float(v.y << 16), a[2]);
                    a[3] = fmaf(dvc, __uint_as_float(v.y & 0xffff0000u), a[3]);
                    a[4] = fmaf(dvc, __uint_as_float(v.z << 16), a[4]);
                    a[5] = fmaf(dvc, __uint_as_float(v.z & 0xffff0000u), a[5]);
                    a[6] = fmaf(dvc, __uint_as_float(v.w << 16), a[6]);
                    a[7] = fmaf(dvc, __uint_as_float(v.w & 0xffff0000u), a[7]);
                }
            }
        }
#pragma unroll
        for (int m = 8; m <= 32; m <<= 1) {
#pragma unroll
            for (int i = 0; i < 8; ++i)
                a[i] += __shfl_xor(a[i], m);
        }
        float dv = dl[ln];
        int n = (b << FSHIFT) + ln;
        if (g < 2) {
            int o = g * 4;
            fvec4 r;
            r.x = fmaxf(fmaf(dv, a[o + 0], bj[o + 0]), 0.0f);
            r.y = fmaxf(fmaf(dv, a[o + 1], bj[o + 1]), 0.0f);
            r.z = fmaxf(fmaf(dv, a[o + 2], bj[o + 2]), 0.0f);
            r.w = fmaxf(fmaf(dv, a[o + 3], bj[o + 3]), 0.0f);
            __builtin_nontemporal_store(r, (fvec4*)(out + (size_t)n * D + q * 8 + o));
        }
    }
}

extern "C" void kernel_launch(void* const* d_in, const int* in_sizes, int n_in,
                              void* d_out, int out_size, void* d_ws, size_t ws_size,
                              hipStream_t stream) {
    const float* x    = (const float*)d_in[0];
    const int*   eidx = (const int*)d_in[1];
    const float* W    = (const float*)d_in[2];
    const float* b    = (const float*)d_in[3];
    float* out = (float*)d_out;
    char* ws = (char*)d_ws;

    const int* row = eidx;
    const int* col = eidx + N_EDGES;

    int*   ccur   = (int*)  (ws + CCUR_OFF);
    int*   fcur   = (int*)  (ws + FCUR_OFF);
    float* dinv   = (float*)(ws + DINV_OFF);
    unsigned short* y = (unsigned short*)(ws + Y_OFF);
    int*   cpairs = (int*)  (ws + CPAIRS_OFF);
    int*   fpairs = (int*)  (ws + FPAIRS_OFF);

    hipMemsetAsync(ws, 0, INIT_BYTES, stream);
    saxf_kernel<<<NCHUNKA + XFA, 256, 0, stream>>>(row, col, ccur, cpairs, x, W, y);
    dsbxf_kernel<<<NCB + NSB + XFB, 256, 0, stream>>>(cpairs, ccur, fcur, fpairs, dinv, x, W, y);
    mega_kernel<<<NFB, 256, 0, stream>>>(fpairs, fcur, y, dinv, b, out);
}